// Round 1
// 679.847 us; speedup vs baseline: 1.0969x; 1.0969x over previous
//
#include <hip/hip_runtime.h>
#include <hip/hip_bf16.h>

#define Bn 8
#define Nn 256
#define Fn 128
#define Dn 128

typedef __bf16 bf16_t;
typedef bf16_t bf16x8 __attribute__((ext_vector_type(8)));
typedef float f32x4 __attribute__((ext_vector_type(4)));

// ---------------------------------------------------------------------------
// Fused [rows x 256] x [256 x 128] GEMMs, A = [X1 | X2] concat on k.
// fp32 in/out; bf16 MFMA 16x16x32 with fp32 accumulate.
//
// One dispatch covers the edge GEMM (2048 tiles) AND the three node GEMMs
// (24 tiles) so the tiny node GEMMs hide under the big one.
//
// 512-thread blocks (8 waves) share ONE 64KB W staging -> 2 blocks/CU =
// 16 waves/CU (was 8), doubling latency-hiding occupancy.
//
// LDS layout: element W[k][n] at lds[n*256 + cp*8 + (k&7)],
//   cp = (k>>3) ^ (n&7) ^ ((n>>3)&7)
// The extra ^((n>>3)&7) term (vs previous kernel) puts the lane-varying
// n-high bits into the bank index on the STAGING WRITE side (was a 16-way
// conflict = 4e7 SQ_LDS_BANK_CONFLICT); read side stays 2-way (free).
// Staging also register-transposes 8x8 blocks -> 8 ds_write_b128/thread
// instead of 128 scalar ds_write_u16.
// ---------------------------------------------------------------------------
__global__ __launch_bounds__(512, 4) void mfma_gemm_kernel(
    const float* __restrict__ edge, const float* __restrict__ ehid,
    const float* __restrict__ We,   const float* __restrict__ be,
    const float* __restrict__ node, const float* __restrict__ hidden,
    const float* __restrict__ W_m1, const float* __restrict__ b_m1,
    const float* __restrict__ W_m2, const float* __restrict__ b_m2,
    const float* __restrict__ W_o1, const float* __restrict__ b_o1,
    float* __restrict__ out_et,
    float* __restrict__ ws_m1, float* __restrict__ ws_m2, float* __restrict__ ws_h1)
{
    __shared__ __align__(16) bf16_t lds[128 * 256];  // 64KB

    const int t = threadIdx.x;

    // ---- job select (wave-uniform) ----
    const float *X1, *X2, *W, *bias;
    float* out;
    long rowbase;
    if (blockIdx.x < 2048) {
        X1 = edge; X2 = ehid; W = We; bias = be; out = out_et;
        rowbase = (long)blockIdx.x * 256;
    } else {
        const int e = blockIdx.x - 2048;
        const int w = e >> 3;                 // which weight set
        rowbase = (long)(e & 7) * 256;
        X1 = node; X2 = hidden;
        if (w == 0)      { W = W_m2; bias = b_m2; out = ws_m2; }
        else if (w == 1) { W = W_m1; bias = b_m1; out = ws_m1; }
        else             { W = W_o1; bias = b_o1; out = ws_h1; }
    }

    // ---- stage W (fp32 global -> bf16 LDS, swizzled) ----
    // 512 threads cover 32 k-blocks x 16 n-octs; each thread: 8x8 block.
    {
        const int kb = t >> 4;       // k-block of 8 rows   (0..31)
        const int g  = t & 15;       // n-oct               (0..15)
        const float* wp = W + (kb * 8) * 128 + g * 8;
        float buf[8][8];
        #pragma unroll
        for (int r = 0; r < 8; ++r) {
            f32x4 u0 = *(const f32x4*)(wp + r * 128);
            f32x4 u1 = *(const f32x4*)(wp + r * 128 + 4);
            buf[r][0] = u0[0]; buf[r][1] = u0[1]; buf[r][2] = u0[2]; buf[r][3] = u0[3];
            buf[r][4] = u1[0]; buf[r][5] = u1[1]; buf[r][6] = u1[2]; buf[r][7] = u1[3];
        }
        #pragma unroll
        for (int j = 0; j < 8; ++j) {
            const int n  = g * 8 + j;
            const int cp = kb ^ j ^ (g & 7);   // = kb ^ (n&7) ^ ((n>>3)&7)
            bf16x8 w8;
            #pragma unroll
            for (int r = 0; r < 8; ++r) w8[r] = (bf16_t)buf[r][j];
            *(bf16x8*)(&lds[n * 256 + cp * 8]) = w8;   // b128, 2-way banks (free)
        }
    }
    __syncthreads();

    const int wv     = t >> 6;       // 0..7
    const int l      = t & 63;
    const int lane16 = l & 15;
    const int quad   = l >> 4;

    float bev[8];
    #pragma unroll
    for (int nt = 0; nt < 8; ++nt) bev[nt] = bias[nt * 16 + lane16];

    const long wrow = rowbase + wv * 32;     // 32 rows per wave, 2 its of 16

    for (int it = 0; it < 2; ++it) {
        const long rbase = wrow + it * 16;
        const long arow  = rbase + lane16;
        const float* pe = X1 + arow * 128 + quad * 8;
        const float* ph = X2 + arow * 128 + quad * 8;

        // a[kk] holds A[row][kk*32 + quad*8 + j]  (bf16-rounded)
        bf16x8 a[8];
        #pragma unroll
        for (int kk = 0; kk < 4; ++kk) {
            f32x4 u0 = *(const f32x4*)(pe + kk * 32);
            f32x4 u1 = *(const f32x4*)(pe + kk * 32 + 4);
            bf16x8 aa;
            #pragma unroll
            for (int j = 0; j < 4; ++j) { aa[j] = (bf16_t)u0[j]; aa[j + 4] = (bf16_t)u1[j]; }
            a[kk] = aa;
        }
        #pragma unroll
        for (int kk = 0; kk < 4; ++kk) {
            f32x4 u0 = *(const f32x4*)(ph + kk * 32);
            f32x4 u1 = *(const f32x4*)(ph + kk * 32 + 4);
            bf16x8 aa;
            #pragma unroll
            for (int j = 0; j < 4; ++j) { aa[j] = (bf16_t)u0[j]; aa[j + 4] = (bf16_t)u1[j]; }
            a[kk + 4] = aa;
        }

        f32x4 acc[8];
        #pragma unroll
        for (int nt = 0; nt < 8; ++nt) acc[nt] = (f32x4){0.f, 0.f, 0.f, 0.f};

        #pragma unroll
        for (int kk = 0; kk < 8; ++kk) {
            #pragma unroll
            for (int nt = 0; nt < 8; ++nt) {
                const int n  = nt * 16 + lane16;
                const int c  = kk * 4 + quad;
                const int cp = c ^ (n & 7) ^ ((n >> 3) & 7);
                bf16x8 bfrag = *(const bf16x8*)(&lds[n * 256 + cp * 8]);
                acc[nt] = __builtin_amdgcn_mfma_f32_16x16x32_bf16(a[kk], bfrag, acc[nt], 0, 0, 0);
            }
        }

        // D layout: col = lane&15, row = quad*4 + reg
        const long orow0 = rbase + quad * 4;
        #pragma unroll
        for (int nt = 0; nt < 8; ++nt) {
            #pragma unroll
            for (int r = 0; r < 4; ++r) {
                out[(orow0 + r) * 128 + nt * 16 + lane16] = acc[nt][r] + bev[nt];
            }
        }
    }
}

// ---------------------------------------------------------------------------
// per (b,j):  mx[d] = max(b_m2[d], max_{i: adj[b,i,j]>0} m2[b,i,d])
//             ret   = h1[b,j,d] + b_o2[d] + sum_k (m1[b,j,k]+mx[k]) * W_o2[k][d]
// Branchless max loop: unconditional loads (L2-hot) + cndmask, so loads
// pipeline instead of serializing on a per-iteration uniform branch.
// ---------------------------------------------------------------------------
__global__ void ret_kernel(
    const int* __restrict__ adj,
    const float* __restrict__ m2, const float* __restrict__ m1,
    const float* __restrict__ h1,
    const float* __restrict__ W_o2, const float* __restrict__ b_o2,
    const float* __restrict__ b_m2,
    float* __restrict__ out)
{
    __shared__ float sv[128];
    __shared__ int adjc[256];

    const int bj = blockIdx.x;       // b*N + j
    const int b  = bj >> 8;
    const int j  = bj & 255;
    const int d  = threadIdx.x;      // 0..127

    adjc[d]       = adj[(b * 256 + d) * 256 + j];
    adjc[d + 128] = adj[(b * 256 + d + 128) * 256 + j];
    __syncthreads();

    // virtual node (always connected, zero features) contributes b_m2
    float mx = b_m2[d];
    const float* m2b = m2 + (long)b * 256 * 128 + d;
    #pragma unroll 4
    for (int i = 0; i < 256; ++i) {
        const float v = adjc[i] ? m2b[i * 128] : -3.0e38f;
        mx = fmaxf(mx, v);
    }

    sv[d] = m1[bj * 128 + d] + mx;
    __syncthreads();

    float r = h1[bj * 128 + d] + b_o2[d];
    #pragma unroll 8
    for (int k = 0; k < 128; ++k)
        r += sv[k] * W_o2[k * 128 + d];

    out[bj * 128 + d] = r;
}

// ---------------------------------------------------------------------------
extern "C" void kernel_launch(void* const* d_in, const int* in_sizes, int n_in,
                              void* d_out, int out_size, void* d_ws, size_t ws_size,
                              hipStream_t stream)
{
    const float* node   = (const float*)d_in[0];
    const float* edge   = (const float*)d_in[1];
    // d_in[2] graph_fts: unused by the reference
    const int*   adj    = (const int*)d_in[3];
    const float* hidden = (const float*)d_in[4];
    const float* ehid   = (const float*)d_in[5];
    const float* We     = (const float*)d_in[6];
    const float* be     = (const float*)d_in[7];
    const float* W_m1   = (const float*)d_in[8];
    const float* b_m1   = (const float*)d_in[9];
    const float* W_m2   = (const float*)d_in[10];
    const float* b_m2   = (const float*)d_in[11];
    const float* W_o1   = (const float*)d_in[12];
    const float* b_o1   = (const float*)d_in[13];
    const float* W_o2   = (const float*)d_in[14];
    const float* b_o2   = (const float*)d_in[15];

    float* out_ret = (float*)d_out;                     // [8,256,128]
    float* out_et  = (float*)d_out + Bn * Nn * Dn;      // [8,256,256,128]

    float* ws_m2 = (float*)d_ws;                        // [2048,128]
    float* ws_m1 = ws_m2 + 2048 * 128;
    float* ws_h1 = ws_m1 + 2048 * 128;                  // 3 MB total

    // One fused dispatch: 2048 edge tiles + 24 node tiles (3 weight sets x 8)
    hipLaunchKernelGGL(mfma_gemm_kernel, dim3(2048 + 24), dim3(512), 0, stream,
                       edge, ehid, We, be, node, hidden,
                       W_m1, b_m1, W_m2, b_m2, W_o1, b_o1,
                       out_et, ws_m1, ws_m2, ws_h1);
    // adjacency max + output GEMV
    hipLaunchKernelGGL(ret_kernel, dim3(2048), dim3(128), 0, stream,
                       adj, ws_m2, ws_m1, ws_h1, W_o2, b_o2, b_m2, out_ret);
}

// Round 2
// 672.303 us; speedup vs baseline: 1.1092x; 1.0112x over previous
//
#include <hip/hip_runtime.h>
#include <hip/hip_bf16.h>

#define Bn 8
#define Nn 256
#define Fn 128
#define Dn 128

typedef __bf16 bf16_t;
typedef bf16_t bf16x8 __attribute__((ext_vector_type(8)));
typedef float f32x4 __attribute__((ext_vector_type(4)));

// ---------------------------------------------------------------------------
// Fused [rows x 256] x [256 x 128] GEMMs, A = [X1 | X2] concat on k.
// fp32 in/out; bf16 MFMA 16x16x32 with fp32 accumulate.
//
// Round-2 change: CHUNK-PIPELINED inner loop. Round 1 showed VGPR=64 ->
// compiler was recycling a tiny load buffer: burst 2-4 loads, drain, long
// compute with nothing in flight => 44% memory duty cycle (2.77 TB/s of
// 6.3 achievable) while MfmaUtil/VALUBusy ~6%. Now each 16-row sub-iter is
// 8 k-chunks (2 x f32x4 loads -> cvt -> 8 MFMA); a 2-chunk rolling prefetch
// (explicit double-buffer regs, fully unrolled so indices are static) keeps
// 4 loads continuously in flight per wave. 16 waves/CU x 4 KB >> the ~9 KB
// per CU Little's-law requirement for full HBM BW.
// ---------------------------------------------------------------------------
__global__ __launch_bounds__(512, 4) void mfma_gemm_kernel(
    const float* __restrict__ edge, const float* __restrict__ ehid,
    const float* __restrict__ We,   const float* __restrict__ be,
    const float* __restrict__ node, const float* __restrict__ hidden,
    const float* __restrict__ W_m1, const float* __restrict__ b_m1,
    const float* __restrict__ W_m2, const float* __restrict__ b_m2,
    const float* __restrict__ W_o1, const float* __restrict__ b_o1,
    float* __restrict__ out_et,
    float* __restrict__ ws_m1, float* __restrict__ ws_m2, float* __restrict__ ws_h1)
{
    __shared__ __align__(16) bf16_t lds[128 * 256];  // 64KB

    const int t = threadIdx.x;

    // ---- job select (block-uniform) ----
    const float *X1, *X2, *W, *bias;
    float* out;
    long rowbase;
    bool streaming;                      // edge job: output never re-read
    if (blockIdx.x < 2048) {
        X1 = edge; X2 = ehid; W = We; bias = be; out = out_et;
        rowbase = (long)blockIdx.x * 256;
        streaming = true;
    } else {
        const int e = blockIdx.x - 2048;
        const int w = e >> 3;                 // which weight set
        rowbase = (long)(e & 7) * 256;
        X1 = node; X2 = hidden;
        streaming = false;
        if (w == 0)      { W = W_m2; bias = b_m2; out = ws_m2; }
        else if (w == 1) { W = W_m1; bias = b_m1; out = ws_m1; }
        else             { W = W_o1; bias = b_o1; out = ws_h1; }
    }

    // ---- stage W (fp32 global -> bf16 LDS, swizzled) ----
    // element W[k][n] at lds[n*256 + cp*8 + (k&7)], cp = (k>>3)^(n&7)^((n>>3)&7)
    {
        const int kb = t >> 4;       // k-block of 8 rows   (0..31)
        const int g  = t & 15;       // n-oct               (0..15)
        const float* wp = W + (kb * 8) * 128 + g * 8;
        float buf[8][8];
        #pragma unroll
        for (int r = 0; r < 8; ++r) {
            f32x4 u0 = *(const f32x4*)(wp + r * 128);
            f32x4 u1 = *(const f32x4*)(wp + r * 128 + 4);
            buf[r][0] = u0[0]; buf[r][1] = u0[1]; buf[r][2] = u0[2]; buf[r][3] = u0[3];
            buf[r][4] = u1[0]; buf[r][5] = u1[1]; buf[r][6] = u1[2]; buf[r][7] = u1[3];
        }
        #pragma unroll
        for (int j = 0; j < 8; ++j) {
            const int n  = g * 8 + j;
            const int cp = kb ^ j ^ (g & 7);
            bf16x8 w8;
            #pragma unroll
            for (int r = 0; r < 8; ++r) w8[r] = (bf16_t)buf[r][j];
            *(bf16x8*)(&lds[n * 256 + cp * 8]) = w8;
        }
    }
    __syncthreads();

    const int wv     = t >> 6;       // 0..7
    const int l      = t & 63;
    const int lane16 = l & 15;
    const int quad   = l >> 4;

    float bev[8];
    #pragma unroll
    for (int nt = 0; nt < 8; ++nt) bev[nt] = bias[nt * 16 + lane16];

    const long wrow = rowbase + wv * 32;     // 32 rows per wave: 2 sub-iters of 16

    const float* base1 = X1 + (wrow + lane16) * 128 + quad * 8;
    const float* base2 = X2 + (wrow + lane16) * 128 + quad * 8;

    // chunk (s,c): s = sub-iter (0..1), c = k-chunk (0..7).
    // a-frag covers A[row][c*32 + quad*8 .. +7]; c<4 from X1, c>=4 from X2.
    #define CHUNK_PTR(s, c) (((c) < 4 ? base1 : base2) + (s) * 16 * 128 + ((c) & 3) * 32)

    f32x4 u0[2], u1[2];          // rolling double buffer (static-indexed)
    { const float* p = CHUNK_PTR(0, 0); u0[0] = *(const f32x4*)p; u1[0] = *(const f32x4*)(p + 4); }
    { const float* p = CHUNK_PTR(0, 1); u0[1] = *(const f32x4*)p; u1[1] = *(const f32x4*)(p + 4); }

    f32x4 acc[8];
    #pragma unroll
    for (int nt = 0; nt < 8; ++nt) acc[nt] = (f32x4){0.f, 0.f, 0.f, 0.f};

    #pragma unroll
    for (int cc = 0; cc < 16; ++cc) {           // 2 sub-iters x 8 chunks, flat
        const int s  = cc >> 3;
        const int c  = cc & 7;
        const int pb = cc & 1;

        // convert current buffer -> a-frag (frees the buffer regs)
        bf16x8 afrag;
        #pragma unroll
        for (int j = 0; j < 4; ++j) {
            afrag[j]     = (bf16_t)u0[pb][j];
            afrag[j + 4] = (bf16_t)u1[pb][j];
        }

        // prefetch chunk cc+2 into the just-freed buffer
        if (cc + 2 < 16) {
            const int s2 = (cc + 2) >> 3, c2 = (cc + 2) & 7;
            const float* p = CHUNK_PTR(s2, c2);
            u0[pb] = *(const f32x4*)p;
            u1[pb] = *(const f32x4*)(p + 4);
        }

        // 8 MFMAs against staged W
        #pragma unroll
        for (int nt = 0; nt < 8; ++nt) {
            const int n    = nt * 16 + lane16;
            const int cidx = c * 4 + quad;
            const int cp   = cidx ^ (n & 7) ^ ((n >> 3) & 7);
            bf16x8 bfrag = *(const bf16x8*)(&lds[n * 256 + cp * 8]);
            acc[nt] = __builtin_amdgcn_mfma_f32_16x16x32_bf16(afrag, bfrag, acc[nt], 0, 0, 0);
        }

        // sub-iter boundary: store 16 rows, reset acc
        if (c == 7) {
            const long orow0 = wrow + s * 16 + quad * 4;
            #pragma unroll
            for (int nt = 0; nt < 8; ++nt) {
                #pragma unroll
                for (int r = 0; r < 4; ++r) {
                    const float v = acc[nt][r] + bev[nt];
                    float* p = out + (orow0 + r) * 128 + nt * 16 + lane16;
                    if (streaming) __builtin_nontemporal_store(v, p);
                    else           *p = v;
                }
            }
            #pragma unroll
            for (int nt = 0; nt < 8; ++nt) acc[nt] = (f32x4){0.f, 0.f, 0.f, 0.f};
        }
    }
    #undef CHUNK_PTR
}

// ---------------------------------------------------------------------------
// per (b,j):  mx[d] = max(b_m2[d], max_{i: adj[b,i,j]>0} m2[b,i,d])
//             ret   = h1[b,j,d] + b_o2[d] + sum_k (m1[b,j,k]+mx[k]) * W_o2[k][d]
//
// Round-2 rewrite: the old version was one serial 256-iter scan + 128-iter
// GEMV per thread -> latency-bound. Now 256 threads: 8 i-slices x 32-lane
// d-groups with f32x4 loads (8 independent x4-loads in flight per thread),
// LDS tree-reduce across slices, then a 2-way k-split GEMV.
// ---------------------------------------------------------------------------
__global__ __launch_bounds__(256) void ret_kernel(
    const int* __restrict__ adj,
    const float* __restrict__ m2, const float* __restrict__ m1,
    const float* __restrict__ h1,
    const float* __restrict__ W_o2, const float* __restrict__ b_o2,
    const float* __restrict__ b_m2,
    float* __restrict__ out)
{
    __shared__ int   adjc[256];
    __shared__ float part[8][128];   // 4 KB slice partials
    __shared__ float sv[128];

    const int bj = blockIdx.x;       // b*N + j
    const int b  = bj >> 8;
    const int j  = bj & 255;
    const int t  = threadIdx.x;      // 0..255

    adjc[t] = adj[(b * 256 + t) * 256 + j];
    __syncthreads();

    // masked max: slice s covers i in [s*32, s*32+32), d-group dg covers 4 d's
    const int s  = t >> 5;           // 0..7
    const int dg = t & 31;           // 0..31
    f32x4 mx4;
    mx4[0] = mx4[1] = mx4[2] = mx4[3] = -3.0e38f;
    const float* m2p = m2 + ((long)b * 256 + s * 32) * 128 + dg * 4;
    #pragma unroll 8
    for (int i = 0; i < 32; ++i) {
        const f32x4 v = *(const f32x4*)(m2p + i * 128);   // unconditional, pipelines
        const bool on = (adjc[s * 32 + i] != 0);
        mx4[0] = on ? fmaxf(mx4[0], v[0]) : mx4[0];
        mx4[1] = on ? fmaxf(mx4[1], v[1]) : mx4[1];
        mx4[2] = on ? fmaxf(mx4[2], v[2]) : mx4[2];
        mx4[3] = on ? fmaxf(mx4[3], v[3]) : mx4[3];
    }
    *(f32x4*)&part[s][dg * 4] = mx4;
    __syncthreads();

    if (t < 128) {
        float m = b_m2[t];           // virtual node (always connected, zero feats)
        #pragma unroll
        for (int ss = 0; ss < 8; ++ss) m = fmaxf(m, part[ss][t]);
        sv[t] = m1[bj * 128 + t] + m;
    }
    __syncthreads();

    // GEMV: thread (h,d): half h sums k in [h*64, h*64+64)
    const int d = t & 127;
    const int h = t >> 7;
    float r = 0.f;
    const float* wp = W_o2 + (h * 64) * 128 + d;
    #pragma unroll 8
    for (int k = 0; k < 64; ++k)
        r += sv[h * 64 + k] * wp[k * 128];

    if (h == 1) part[0][d] = r;
    __syncthreads();
    if (h == 0)
        out[bj * 128 + d] = r + part[0][d] + h1[bj * 128 + d] + b_o2[d];
}

// ---------------------------------------------------------------------------
extern "C" void kernel_launch(void* const* d_in, const int* in_sizes, int n_in,
                              void* d_out, int out_size, void* d_ws, size_t ws_size,
                              hipStream_t stream)
{
    const float* node   = (const float*)d_in[0];
    const float* edge   = (const float*)d_in[1];
    // d_in[2] graph_fts: unused by the reference
    const int*   adj    = (const int*)d_in[3];
    const float* hidden = (const float*)d_in[4];
    const float* ehid   = (const float*)d_in[5];
    const float* We     = (const float*)d_in[6];
    const float* be     = (const float*)d_in[7];
    const float* W_m1   = (const float*)d_in[8];
    const float* b_m1   = (const float*)d_in[9];
    const float* W_m2   = (const float*)d_in[10];
    const float* b_m2   = (const float*)d_in[11];
    const float* W_o1   = (const float*)d_in[12];
    const float* b_o1   = (const float*)d_in[13];
    const float* W_o2   = (const float*)d_in[14];
    const float* b_o2   = (const float*)d_in[15];

    float* out_ret = (float*)d_out;                     // [8,256,128]
    float* out_et  = (float*)d_out + Bn * Nn * Dn;      // [8,256,256,128]

    float* ws_m2 = (float*)d_ws;                        // [2048,128]
    float* ws_m1 = ws_m2 + 2048 * 128;
    float* ws_h1 = ws_m1 + 2048 * 128;                  // 3 MB total

    // One fused dispatch: 2048 edge tiles + 24 node tiles (3 weight sets x 8)
    hipLaunchKernelGGL(mfma_gemm_kernel, dim3(2048 + 24), dim3(512), 0, stream,
                       edge, ehid, We, be, node, hidden,
                       W_m1, b_m1, W_m2, b_m2, W_o1, b_o1,
                       out_et, ws_m1, ws_m2, ws_h1);
    // adjacency max + output GEMV
    hipLaunchKernelGGL(ret_kernel, dim3(2048), dim3(256), 0, stream,
                       adj, ws_m2, ws_m1, ws_h1, W_o2, b_o2, b_m2, out_ret);
}

// Round 3
// 643.355 us; speedup vs baseline: 1.1592x; 1.0450x over previous
//
#include <hip/hip_runtime.h>
#include <hip/hip_bf16.h>

#define Bn 8
#define Nn 256
#define Fn 128
#define Dn 128

typedef __bf16 bf16_t;
typedef bf16_t bf16x8 __attribute__((ext_vector_type(8)));
typedef bf16_t bf16x4 __attribute__((ext_vector_type(4)));
typedef float f32x4 __attribute__((ext_vector_type(4)));

#define GLOAD16(g, l) __builtin_amdgcn_global_load_lds(                        \
    (const __attribute__((address_space(1))) void*)(g),                        \
    (__attribute__((address_space(3))) void*)(l), 16, 0, 0)

// ---------------------------------------------------------------------------
// Fused [rows x 256] x [256 x 128] GEMMs, A = [X1 | X2] concat on k.
// fp32 in/out; bf16 MFMA 16x16x32 with fp32 accumulate.
//
// Round-3: ASYNC A-STAGING. Rounds 1-2 proved register-staged A loads get
// serialized by regalloc (VGPR pinned at 64 -> ~2 loads in flight -> 36% HBM).
// Now A streams via global_load_lds (zero VGPR, fire-and-forget) into
// wave-private LDS chunk buffers (16 rows x 32 k fp32 = 2 KB, double-buffered)
// with counted s_waitcnt vmcnt(2) -- the load queue never drains in the loop,
// and there are NO barriers in the main loop (chunks are wave-private).
//
// 1024 threads = 16 waves x 16 rows. LDS = 64 KB W (bf16, swizzled) +
// 16 waves x 2 x 2 KB A = 128 KB -> 1 block/CU, 4 waves/SIMD.
//
// A LDS layout: global_load_lds writes linearly (base + lane*16), so the
// per-lane GLOBAL source is pre-swizzled: slot s holds A[row = s>>3]
// [kgrp = (s&7) ^ (row&7)] (4 floats). Read side applies the same XOR ->
// each ds_read_b128 spreads 64 lanes uniformly over all 32 banks.
// ---------------------------------------------------------------------------
__global__ __launch_bounds__(1024, 4) void mfma_gemm_kernel(
    const float* __restrict__ edge, const float* __restrict__ ehid,
    const float* __restrict__ We,   const float* __restrict__ be,
    const float* __restrict__ node, const float* __restrict__ hidden,
    const float* __restrict__ W_m1, const float* __restrict__ b_m1,
    const float* __restrict__ W_m2, const float* __restrict__ b_m2,
    const float* __restrict__ W_o1, const float* __restrict__ b_o1,
    float* __restrict__ out_et,
    float* __restrict__ ws_m1, float* __restrict__ ws_m2, float* __restrict__ ws_h1)
{
    __shared__ __align__(16) char smem[131072];
    bf16_t* wlds = (bf16_t*)smem;               // 64 KB: W bf16, swizzled
    float*  albs = (float*)(smem + 65536);      // 64 KB: A chunks, 16w x 2 x 512 f

    const int t = threadIdx.x;

    // ---- job select (block-uniform); node jobs first so they mix into round 0
    const float *X1, *X2, *W, *bias;
    float* out;
    long rowbase;
    bool streaming;
    if (blockIdx.x >= 24) {
        X1 = edge; X2 = ehid; W = We; bias = be; out = out_et;
        rowbase = (long)(blockIdx.x - 24) * 256;
        streaming = true;                        // output never re-read
    } else {
        const int e = blockIdx.x;
        const int w = e >> 3;
        rowbase = (long)(e & 7) * 256;
        X1 = node; X2 = hidden; streaming = false;
        if (w == 0)      { W = W_m2; bias = b_m2; out = ws_m2; }
        else if (w == 1) { W = W_m1; bias = b_m1; out = ws_m1; }
        else             { W = W_o1; bias = b_o1; out = ws_h1; }
    }

    const int wv     = t >> 6;        // 0..15
    const int l      = t & 63;
    const int lane16 = l & 15;
    const int quad   = l >> 4;

    const long wrow = rowbase + wv * 16;   // 16 rows per wave

    // per-lane A gather pattern (pre-swizzled source -> swizzled linear LDS)
    const int arow0 = l >> 3;                      // 0..7 (second instr: +8)
    const int akg   = (l & 7) ^ (arow0 & 7);       // kgrp this lane fetches
    const float* aX1 = X1 + (wrow + arow0) * 128 + akg * 4;
    const float* aX2 = X2 + (wrow + arow0) * 128 + akg * 4;
    float* abw = albs + wv * 1024;                 // wave region: 2 x 512 floats

    // issue chunk c (k in [c*32, c*32+32)) into buffer b: 2 x global_load_lds,
    // each covers 8 rows x 32 k (64 lanes x 16 B = 1 KB)
#define ISSUE_CHUNK(c_, b_) do {                                              \
        const float* s_ = ((c_) < 4) ? (aX1 + (c_) * 32)                      \
                                     : (aX2 + ((c_) - 4) * 32);               \
        float* d_ = abw + (b_) * 512;                                         \
        GLOAD16(s_,        d_);                                               \
        GLOAD16(s_ + 1024, d_ + 256);   /* rows +8: +8*128 floats */          \
    } while (0)

    // prologue: chunks 0,1 in flight; their latency hides under W staging
    ISSUE_CHUNK(0, 0);
    ISSUE_CHUNK(1, 1);

    // ---- stage W (fp32 global -> bf16 LDS, swizzled) ----
    // element W[k][n] at wlds[n*256 + cp*8 + (k&7)], cp = (k>>3)^(n&7)^((n>>3)&7)
    {
        const int kb4 = t >> 4;            // 0..63 -> k0 = kb4*4
        const int g   = t & 15;            // n-oct
        const int k0  = kb4 * 4;
        const float* wp = W + (long)k0 * 128 + g * 8;
        f32x4 a0[4], a1[4];
        #pragma unroll
        for (int r = 0; r < 4; ++r) {
            a0[r] = *(const f32x4*)(wp + r * 128);
            a1[r] = *(const f32x4*)(wp + r * 128 + 4);
        }
        #pragma unroll
        for (int j = 0; j < 8; ++j) {
            const int n  = g * 8 + j;
            const int cp = (kb4 >> 1) ^ j ^ (g & 7);
            bf16x4 v;
            #pragma unroll
            for (int r = 0; r < 4; ++r)
                v[r] = (bf16_t)(j < 4 ? a0[r][j] : a1[r][j - 4]);
            *(bf16x4*)(&wlds[n * 256 + cp * 8 + (k0 & 7)]) = v;
        }
    }
    __syncthreads();

    float bev[8];
    #pragma unroll
    for (int nt = 0; nt < 8; ++nt) bev[nt] = bias[nt * 16 + lane16];

    f32x4 acc[8];
    #pragma unroll
    for (int nt = 0; nt < 8; ++nt) acc[nt] = (f32x4){0.f, 0.f, 0.f, 0.f};

    // A-read offsets (swizzled): row = lane16, kgrps {quad*2, quad*2+1}
    const int kst0 = (quad * 2)     ^ (lane16 & 7);
    const int kst1 = (quad * 2 + 1) ^ (lane16 & 7);

    #pragma unroll
    for (int c = 0; c < 8; ++c) {
        const int b = c & 1;

        // wait for chunk c staged (counted: keep chunk c+1's loads in flight)
        if (c < 7) asm volatile("s_waitcnt vmcnt(2)" ::: "memory");
        else       asm volatile("s_waitcnt vmcnt(0)" ::: "memory");
        __builtin_amdgcn_sched_barrier(0);

        const float* bufp = abw + b * 512 + lane16 * 32;
        f32x4 u0 = *(const f32x4*)(bufp + kst0 * 4);
        f32x4 u1 = *(const f32x4*)(bufp + kst1 * 4);
        bf16x8 afrag;
        #pragma unroll
        for (int j = 0; j < 4; ++j) {
            afrag[j]     = (bf16_t)u0[j];
            afrag[j + 4] = (bf16_t)u1[j];
        }

        // WAR fence: A reads must retire before chunk c+2 overwrites buffer b
        asm volatile("s_waitcnt lgkmcnt(0)" ::: "memory");
        __builtin_amdgcn_sched_barrier(0);
        if (c + 2 < 8) ISSUE_CHUNK(c + 2, b);

        #pragma unroll
        for (int nt = 0; nt < 8; ++nt) {
            const int n    = nt * 16 + lane16;
            const int cidx = c * 4 + quad;
            const int cp   = cidx ^ (n & 7) ^ ((n >> 3) & 7);
            bf16x8 bfrag = *(const bf16x8*)(&wlds[n * 256 + cp * 8]);
            acc[nt] = __builtin_amdgcn_mfma_f32_16x16x32_bf16(afrag, bfrag, acc[nt], 0, 0, 0);
        }
    }
#undef ISSUE_CHUNK

    // D layout: col = lane&15, row = quad*4 + reg
    const long orow0 = wrow + quad * 4;
    #pragma unroll
    for (int nt = 0; nt < 8; ++nt) {
        #pragma unroll
        for (int r = 0; r < 4; ++r) {
            const float v = acc[nt][r] + bev[nt];
            float* p = out + (orow0 + r) * 128 + nt * 16 + lane16;
            if (streaming) __builtin_nontemporal_store(v, p);
            else           *p = v;
        }
    }
}

// ---------------------------------------------------------------------------
// per (b,j):  mx[d] = max(b_m2[d], max_{i: adj[b,i,j]>0} m2[b,i,d])
//             ret   = h1[b,j,d] + b_o2[d] + sum_k (m1[b,j,k]+mx[k]) * W_o2[k][d]
// 256 threads: 8 i-slices x 32-lane d-groups, f32x4 loads, LDS tree-reduce,
// 2-way k-split GEMV. (unchanged from round 2)
// ---------------------------------------------------------------------------
__global__ __launch_bounds__(256) void ret_kernel(
    const int* __restrict__ adj,
    const float* __restrict__ m2, const float* __restrict__ m1,
    const float* __restrict__ h1,
    const float* __restrict__ W_o2, const float* __restrict__ b_o2,
    const float* __restrict__ b_m2,
    float* __restrict__ out)
{
    __shared__ int   adjc[256];
    __shared__ float part[8][128];
    __shared__ float sv[128];

    const int bj = blockIdx.x;       // b*N + j
    const int b  = bj >> 8;
    const int j  = bj & 255;
    const int t  = threadIdx.x;      // 0..255

    adjc[t] = adj[(b * 256 + t) * 256 + j];
    __syncthreads();

    const int s  = t >> 5;           // 0..7
    const int dg = t & 31;           // 0..31
    f32x4 mx4;
    mx4[0] = mx4[1] = mx4[2] = mx4[3] = -3.0e38f;
    const float* m2p = m2 + ((long)b * 256 + s * 32) * 128 + dg * 4;
    #pragma unroll 8
    for (int i = 0; i < 32; ++i) {
        const f32x4 v = *(const f32x4*)(m2p + i * 128);
        const bool on = (adjc[s * 32 + i] != 0);
        mx4[0] = on ? fmaxf(mx4[0], v[0]) : mx4[0];
        mx4[1] = on ? fmaxf(mx4[1], v[1]) : mx4[1];
        mx4[2] = on ? fmaxf(mx4[2], v[2]) : mx4[2];
        mx4[3] = on ? fmaxf(mx4[3], v[3]) : mx4[3];
    }
    *(f32x4*)&part[s][dg * 4] = mx4;
    __syncthreads();

    if (t < 128) {
        float m = b_m2[t];           // virtual node (always connected, zero feats)
        #pragma unroll
        for (int ss = 0; ss < 8; ++ss) m = fmaxf(m, part[ss][t]);
        sv[t] = m1[bj * 128 + t] + m;
    }
    __syncthreads();

    const int d = t & 127;
    const int h = t >> 7;
    float r = 0.f;
    const float* wp = W_o2 + (h * 64) * 128 + d;
    #pragma unroll 8
    for (int k = 0; k < 64; ++k)
        r += sv[h * 64 + k] * wp[k * 128];

    if (h == 1) part[0][d] = r;
    __syncthreads();
    if (h == 0)
        out[bj * 128 + d] = r + part[0][d] + h1[bj * 128 + d] + b_o2[d];
}

// ---------------------------------------------------------------------------
extern "C" void kernel_launch(void* const* d_in, const int* in_sizes, int n_in,
                              void* d_out, int out_size, void* d_ws, size_t ws_size,
                              hipStream_t stream)
{
    const float* node   = (const float*)d_in[0];
    const float* edge   = (const float*)d_in[1];
    // d_in[2] graph_fts: unused by the reference
    const int*   adj    = (const int*)d_in[3];
    const float* hidden = (const float*)d_in[4];
    const float* ehid   = (const float*)d_in[5];
    const float* We     = (const float*)d_in[6];
    const float* be     = (const float*)d_in[7];
    const float* W_m1   = (const float*)d_in[8];
    const float* b_m1   = (const float*)d_in[9];
    const float* W_m2   = (const float*)d_in[10];
    const float* b_m2   = (const float*)d_in[11];
    const float* W_o1   = (const float*)d_in[12];
    const float* b_o1   = (const float*)d_in[13];
    const float* W_o2   = (const float*)d_in[14];
    const float* b_o2   = (const float*)d_in[15];

    float* out_ret = (float*)d_out;                     // [8,256,128]
    float* out_et  = (float*)d_out + Bn * Nn * Dn;      // [8,256,256,128]

    float* ws_m2 = (float*)d_ws;                        // [2048,128]
    float* ws_m1 = ws_m2 + 2048 * 128;
    float* ws_h1 = ws_m1 + 2048 * 128;                  // 3 MB total

    // One fused dispatch: 24 node tiles (first, to mix into round 0) + 2048 edge tiles
    hipLaunchKernelGGL(mfma_gemm_kernel, dim3(2048 + 24), dim3(1024), 0, stream,
                       edge, ehid, We, be, node, hidden,
                       W_m1, b_m1, W_m2, b_m2, W_o1, b_o1,
                       out_et, ws_m1, ws_m2, ws_h1);
    // adjacency max + output GEMV
    hipLaunchKernelGGL(ret_kernel, dim3(2048), dim3(256), 0, stream,
                       adj, ws_m2, ws_m1, ws_h1, W_o2, b_o2, b_m2, out_ret);
}